// Round 14
// baseline (278.107 us; speedup 1.0000x reference)
//
#include <hip/hip_runtime.h>
#include <hip/hip_bf16.h>

typedef short v8s __attribute__((ext_vector_type(8)));
typedef float v4f __attribute__((ext_vector_type(4)));
typedef __hip_bfloat16 bf16;
typedef unsigned int u32;

#define MFMA(a, b, c) __builtin_amdgcn_mfma_f32_16x16x32_bf16(a, b, c, 0, 0, 0)

// direct global->LDS DMA, 16B per lane. LDS dest = wave-uniform base + lane*16.
__device__ __forceinline__ void gload16(const bf16* g, bf16* l) {
    __builtin_amdgcn_global_load_lds(
        (const __attribute__((address_space(1))) u32*)(g),
        (__attribute__((address_space(3))) u32*)(l), 16, 0, 0);
}

// ---------------------------------------------------------------------------
// All fp32->bf16 casts in ONE launch. grid=(4096,6); region r sized n4 vec4s.
// ---------------------------------------------------------------------------
__global__ __launch_bounds__(256) void cast_all(
    const float* __restrict__ x,  const float* __restrict__ wq,
    const float* __restrict__ wk, const float* __restrict__ wv,
    const float* __restrict__ wo, const float* __restrict__ er,
    bf16* __restrict__ xb,  bf16* __restrict__ wqb, bf16* __restrict__ wkb,
    bf16* __restrict__ wvb, bf16* __restrict__ wob, bf16* __restrict__ erb)
{
    const int r = blockIdx.y;
    const float* s; bf16* d; int n4;
    if      (r == 0) { s = x;  d = xb;  n4 = 1048576; }
    else if (r == 1) { s = wq; d = wqb; n4 = 262144;  }
    else if (r == 2) { s = wk; d = wkb; n4 = 262144;  }
    else if (r == 3) { s = wv; d = wvb; n4 = 262144;  }
    else if (r == 4) { s = wo; d = wob; n4 = 262144;  }
    else             { s = er; d = erb; n4 = 32768;   }
    const int i = blockIdx.x * 256 + threadIdx.x;
    if (i < n4) {
        const float4 v = ((const float4*)s)[i];
        bf16 t[4];
        t[0] = __float2bfloat16(v.x);
        t[1] = __float2bfloat16(v.y);
        t[2] = __float2bfloat16(v.z);
        t[3] = __float2bfloat16(v.w);
        ((uint2*)d)[i] = *(const uint2*)t;
    }
}

// ---------------------------------------------------------------------------
// NT GEMM v4 (unchanged; R6 probe: qkv+proj ~65 us total ~530 TF, structural
// limit for this template at K=1024). s_setprio deliberately NOT applied:
// lockstep 4-wave blocks -> T5 null/negative on GEMM (m190).
// ---------------------------------------------------------------------------
__global__ __launch_bounds__(256) void gemm_nt(
    const bf16* __restrict__ A, const bf16* __restrict__ W,
    const float* __restrict__ b0, const float* __restrict__ b1,
    const float* __restrict__ b2,
    bf16* __restrict__ oHM, bf16* __restrict__ Vt, float* __restrict__ outf)
{
    __shared__ bf16 As[2][128 * 64];
    __shared__ bf16 Bs[2][128 * 64];

    const int tid = threadIdx.x;
    const int w  = tid >> 6, l = tid & 63;
    const int lm = l & 15,  lq = l >> 4;
    const int wm = (w >> 1) * 64, wn = (w & 1) * 64;
    const int m0 = blockIdx.y * 128, n0 = blockIdx.x * 128;

    const int grow = l >> 3;                       // 0..7, == row&7
    const int gcol = ((l & 7) ^ grow) * 8;         // bf16 units, 16B granules

    v4f acc[4][4];
#pragma unroll
    for (int i = 0; i < 4; ++i)
#pragma unroll
        for (int j = 0; j < 4; ++j) acc[i][j] = (v4f){0.f, 0.f, 0.f, 0.f};

    const int sw = (lm & 7) << 4;

    auto STAGE = [&](int p, int k0) {
#pragma unroll
        for (int q = 0; q < 4; ++q) {
            const int rr = w * 32 + q * 8;
            gload16(&A[(size_t)(m0 + rr + grow) * 1024 + k0 + gcol], &As[p][rr * 64]);
            gload16(&W[(size_t)(n0 + rr + grow) * 1024 + k0 + gcol], &Bs[p][rr * 64]);
        }
    };
    auto COMPUTE = [&](int p) {
#pragma unroll
        for (int kk = 0; kk < 2; ++kk) {
            v8s a[4], b[4];
            const int cb = (lq * 16 + kk * 64);
#pragma unroll
            for (int i = 0; i < 4; ++i) {
                const int row = wm + i * 16 + lm;
                a[i] = *(const v8s*)((const char*)As[p] + row * 128 + (cb ^ sw));
            }
#pragma unroll
            for (int j = 0; j < 4; ++j) {
                const int row = wn + j * 16 + lm;
                b[j] = *(const v8s*)((const char*)Bs[p] + row * 128 + (cb ^ sw));
            }
#pragma unroll
            for (int i = 0; i < 4; ++i)
#pragma unroll
                for (int j = 0; j < 4; ++j)
                    acc[i][j] = MFMA(b[j], a[i], acc[i][j]);   // SWAPPED: C^T frag
        }
    };

    STAGE(0, 0);
    __syncthreads();                               // tile 0 landed
    for (int t = 0; t < 15; ++t) {
        STAGE((t + 1) & 1, (t + 1) * 64);          // issue next tile's DMA
        COMPUTE(t & 1);                            // overlap under it
        __syncthreads();                           // drain vmcnt; all reads done
    }
    COMPUTE(1);                                    // tile 15

    const int z = blockIdx.x >> 3;                 // 1024-col slab
    const float* bias = (z == 0) ? b0 : (z == 1) ? b1 : b2;

    float4 bj[4];
#pragma unroll
    for (int j = 0; j < 4; ++j)
        bj[j] = *(const float4*)&bias[(n0 & 1023) + wn + j * 16 + lq * 4];

#pragma unroll
    for (int i = 0; i < 4; ++i) {
        const int row = m0 + wm + i * 16 + lm;     // one row per lane
        const int bb = row >> 11, ss = row & 2047;
#pragma unroll
        for (int j = 0; j < 4; ++j) {
            const int cc = (n0 & 1023) + wn + j * 16 + lq * 4;
            const float v0 = acc[i][j][0] + bj[j].x;
            const float v1 = acc[i][j][1] + bj[j].y;
            const float v2 = acc[i][j][2] + bj[j].z;
            const float v3 = acc[i][j][3] + bj[j].w;
            if (outf) {
                const float4 fv = {v0, v1, v2, v3};
                *(float4*)&outf[(size_t)row * 1024 + cc] = fv;
            } else {
                bf16 t[4];
                t[0] = __float2bfloat16(v0);
                t[1] = __float2bfloat16(v1);
                t[2] = __float2bfloat16(v2);
                t[3] = __float2bfloat16(v3);
                const int hh = cc >> 6, dd = cc & 63;
                if (z < 2) {
                    *(uint2*)&oHM[(size_t)z * 4194304 +
                        ((size_t)(bb * 16 + hh) * 2048 + ss) * 64 + dd] = *(uint2*)t;
                } else {
#pragma unroll
                    for (int r = 0; r < 4; ++r)
                        Vt[((size_t)(bb * 16 + hh) * 64 + dd + r) * 2048 + ss] = t[r];
                }
            }
        }
    }
}

// ---------------------------------------------------------------------------
// Segment schedule tables (48 segments per bh, longest-first).
// TT: 0 = even-parity half, 1 = odd-parity half, 2 = full block.
// ---------------------------------------------------------------------------
__device__ const unsigned char QBt[48] = {
    31,31,30,15, 30,29,29,28,14, 28,27,27,26,13, 26,25,25,24,12,
    24,23,23,22,11, 22,21,21,20,10, 20,19,19,18,9, 18,17,17,16,8,
    16,7, 6,5,4,3,2,1,0};
__device__ const unsigned char TTt[48] = {
     0, 1, 0, 2,  1, 0, 1, 0, 2,  1, 0, 1, 0, 2,  1, 0, 1, 0, 2,
     1, 0, 1, 0, 2,  1, 0, 1, 0, 2,  1, 0, 1, 0, 2,  1, 0, 1, 0, 2,
     1, 2, 2,2,2,2,2,2,2};

// ---------------------------------------------------------------------------
// Flash attention + skewed rel-pos bias, v14 = R13 (best passing: S^T scores,
// dbuf K/V one-barrier, Ps-in-Gs2 overlay, parity split-K) + T5 s_setprio
// around the MFMA-dense body.
// T5 prerequisite (wave phase diversity) holds here in the m191-proven form:
// blocks run INDEPENDENT schedules (different qb lengths/phases), so the 12
// resident waves/CU are at different phases at any instant; setprio(1) lets
// the CU scheduler favor the wave in its MFMA cluster over waves issuing
// staging loads. m191: +4-7% attn in exactly this regime; m190: null on
// lockstep GEMM (so gemm_nt untouched). Zero correctness risk.
// ---------------------------------------------------------------------------
__global__ __launch_bounds__(256, 3) void attn(
    const bf16* __restrict__ Q, const bf16* __restrict__ K,
    const bf16* __restrict__ Vt, const bf16* __restrict__ Er,
    bf16* __restrict__ AO, float* __restrict__ Opart, float* __restrict__ dpart)
{
    __shared__ bf16 Ks[2][64 * 72];
    __shared__ bf16 Vs[2][64 * 72];
    __shared__ bf16 Gs2[64 * 104];  // G band (shifted cols 1..95) + P (cols 0..63)

    const int ord = blockIdx.x;
    const int bh = ord & 31;
    const int s  = ord >> 5;
    const int qb = QBt[s];
    const int tt = TTt[s];
    const int t0   = (tt == 2) ? 0 : tt;           // first tile
    const int step = (tt == 2) ? 1 : 2;            // tile stride
    const int slot = (tt == 2) ? -1 : (((qb - 16) * 32 + bh) * 2 + tt);
    const int N    = (qb - t0) / step + 1;         // iterations

    const int i0 = qb * 64;
    const int b  = bh >> 4, h = bh & 15;
    const int tid = threadIdx.x;
    const int w  = tid >> 6, l = tid & 63;
    const int lm = l & 15,  lq = l >> 4;

    const bf16* qp = Q + ((size_t)bh * 2048 + i0 + w * 16 + lm) * 64 + lq * 8;
    const v8s q0 = *(const v8s*)qp;
    const v8s q1f = *(const v8s*)(qp + 32);

    v4f accO[4];
#pragma unroll
    for (int dt = 0; dt < 4; ++dt) accO[dt] = (v4f){0.f, 0.f, 0.f, 0.f};
    float rsc = 0.f;                   // denominator for q-row i = lm (this lane)

    const int sr0 = tid >> 3;          // 0..31 (+32 on rep1)
    const int sc8 = (tid & 7) * 8;
    const size_t kbase = (size_t)bh * 2048 * 64;
    const size_t vbase = (size_t)bh * 64 * 2048;

    const int grow_g = (w * 16 + lm) * 104;        // this lane's G/P row base
    const int ig     = i0 + w * 16 + lm;           // global q row

    // prologue: stage tile t0 into buf0; prefetch regs <- tile t0+step
    {
        const int jt0 = t0 * 64;
        const uint4 a0 = *(const uint4*)&K[kbase + (size_t)(jt0 + sr0) * 64 + sc8];
        const uint4 a1 = *(const uint4*)&K[kbase + (size_t)(jt0 + sr0 + 32) * 64 + sc8];
        const uint4 c0 = *(const uint4*)&Vt[vbase + (size_t)sr0 * 2048 + jt0 + sc8];
        const uint4 c1 = *(const uint4*)&Vt[vbase + (size_t)(sr0 + 32) * 2048 + jt0 + sc8];
        *(uint4*)&Ks[0][sr0 * 72 + sc8]        = a0;
        *(uint4*)&Ks[0][(sr0 + 32) * 72 + sc8] = a1;
        *(uint4*)&Vs[0][sr0 * 72 + sc8]        = c0;
        *(uint4*)&Vs[0][(sr0 + 32) * 72 + sc8] = c1;
    }
    uint4 kp0, kp1, vp0, vp1;
    if (N > 1) {
        const int jn = (t0 + step) * 64;
        kp0 = *(const uint4*)&K[kbase + (size_t)(jn + sr0) * 64 + sc8];
        kp1 = *(const uint4*)&K[kbase + (size_t)(jn + sr0 + 32) * 64 + sc8];
        vp0 = *(const uint4*)&Vt[vbase + (size_t)sr0 * 2048 + jn + sc8];
        vp1 = *(const uint4*)&Vt[vbase + (size_t)(sr0 + 32) * 2048 + jn + sc8];
    }

    for (int n = 0; n < N; ++n) {
        const int it = t0 + n * step;
        const int j0 = it * 64;
        const int p  = n & 1;
        __syncthreads();   // buf p (staged last iter / prologue) visible;
                           // buf p^1 reads from iter n-1 complete (WAR)
        if (n + 1 < N) {   // stage next tile into buf p^1 from prefetch regs
            bf16* kd = Ks[p ^ 1];
            bf16* vd = Vs[p ^ 1];
            *(uint4*)&kd[sr0 * 72 + sc8]        = kp0;
            *(uint4*)&kd[(sr0 + 32) * 72 + sc8] = kp1;
            *(uint4*)&vd[sr0 * 72 + sc8]        = vp0;
            *(uint4*)&vd[(sr0 + 32) * 72 + sc8] = vp1;
            if (n + 2 < N) {                  // prefetch tile n+2 (distance 2)
                const int jn = (it + 2 * step) * 64;
                kp0 = *(const uint4*)&K[kbase + (size_t)(jn + sr0) * 64 + sc8];
                kp1 = *(const uint4*)&K[kbase + (size_t)(jn + sr0 + 32) * 64 + sc8];
                vp0 = *(const uint4*)&Vt[vbase + (size_t)sr0 * 2048 + jn + sc8];
                vp1 = *(const uint4*)&Vt[vbase + (size_t)(sr0 + 32) * 2048 + jn + sc8];
            }
        }
        __builtin_amdgcn_s_setprio(1);         // T5: favor this wave's MFMA body
        // G band, S^T: MFMA(e,q) -> lane holds q-row lm, col'=ct2*16+lq*4+r;
        // store row-shifted by lm+1 (cols 1..95).
        const int basew = 2048 - 16 - i0 + j0 - 16 * w;
#pragma unroll
        for (int ct2 = 0; ct2 < 5; ++ct2) {
            int mr = basew + ct2 * 16 + lm;
            mr = (mr > 2047) ? 2047 : mr;      // clamped rows feed masked cols only
            const bf16* ep = Er + (size_t)mr * 64 + lq * 8;
            const v8s e0 = *(const v8s*)ep;
            const v8s e1 = *(const v8s*)(ep + 32);
            v4f g = (v4f){0.f, 0.f, 0.f, 0.f};
            g = MFMA(e0, q0, g);
            g = MFMA(e1, q1f, g);
            const int cb = ct2 * 16 + lq * 4 + lm + 1;
#pragma unroll
            for (int r = 0; r < 4; ++r)
                Gs2[grow_g + cb + r] = __float2bfloat16(g[r] * 0.125f);
        }
        // G-store -> G-read: lane-private row; HW DS in-order per wave;
        // compiler fence blocks strict-aliasing reordering (v10's failure mode)
        asm volatile("" ::: "memory");
        // QK^T, S^T from buf p
        v4f sv[4];
#pragma unroll
        for (int ct = 0; ct < 4; ++ct) {
            const v8s k0f = *(const v8s*)&Ks[p][(ct * 16 + lm) * 72 + lq * 8];
            const v8s k1f = *(const v8s*)&Ks[p][(ct * 16 + lm) * 72 + 32 + lq * 8];
            v4f s2 = (v4f){0.f, 0.f, 0.f, 0.f};
            s2 = MFMA(k0f, q0, s2);
            s2 = MFMA(k1f, q1f, s2);
            sv[ct] = s2;
        }
        // scores: G gather (col 16+jj), mask+exp, P^T write into cols jj
        // (overlay: write at ct kills only the G read by this lane at ct-1)
#pragma unroll
        for (int ct = 0; ct < 4; ++ct) {
            const uint2 graw = *(const uint2*)&Gs2[grow_g + 16 + ct * 16 + lq * 4];
            const bf16* gb4 = (const bf16*)&graw;
            bf16 pt[4];
#pragma unroll
            for (int r = 0; r < 4; ++r) {
                const int jj = ct * 16 + lq * 4 + r;
                float sc = fmaf(sv[ct][r], 0.125f, (float)gb4[r]);
                if (j0 + jj > ig) sc = -1e9f;
                const float pe = __expf(sc - 4.0f);
                rsc += pe;
                pt[r] = __float2bfloat16(pe);
            }
            *(uint2*)&Gs2[grow_g + ct * 16 + lq * 4] = *(const uint2*)pt;
        }
        // PV: P from Gs2 cols 0..63 (proven unguarded same-wave pattern),
        // V from buf p
        const v8s pa0 = *(const v8s*)&Gs2[grow_g + lq * 8];
        const v8s pa1 = *(const v8s*)&Gs2[grow_g + 32 + lq * 8];
#pragma unroll
        for (int dt = 0; dt < 4; ++dt) {
            const v8s vb0 = *(const v8s*)&Vs[p][(dt * 16 + lm) * 72 + lq * 8];
            const v8s vb1 = *(const v8s*)&Vs[p][(dt * 16 + lm) * 72 + 32 + lq * 8];
            accO[dt] = MFMA(pa0, vb0, accO[dt]);
            accO[dt] = MFMA(pa1, vb1, accO[dt]);
        }
        __builtin_amdgcn_s_setprio(0);         // T5: release priority for staging
    }
    // denominator: sum the 4 lq replicas of row lm, broadcast to acc rows
    rsc += __shfl_xor(rsc, 16, 64);
    rsc += __shfl_xor(rsc, 32, 64);
    float den[4];
#pragma unroll
    for (int r = 0; r < 4; ++r) den[r] = __shfl(rsc, lq * 4 + r, 64);

    if (slot < 0) {
        // sole owner: normalize and store bf16
#pragma unroll
        for (int dt = 0; dt < 4; ++dt) {
#pragma unroll
            for (int r = 0; r < 4; ++r) {
                const int row = i0 + w * 16 + lq * 4 + r;
                const int d   = dt * 16 + lm;
                AO[((size_t)b * 2048 + row) * 1024 + h * 64 + d] =
                    __float2bfloat16(accO[dt][r] / den[r]);
            }
        }
    } else {
        // parity half: fp32 partials to a private slot (no atomics)
        float* op = Opart + (size_t)slot * 4096;
#pragma unroll
        for (int dt = 0; dt < 4; ++dt) {
#pragma unroll
            for (int r = 0; r < 4; ++r) {
                const int row = w * 16 + lq * 4 + r;
                op[row * 64 + dt * 16 + lm] = accO[dt][r];
            }
        }
        if (lm == 0) {
#pragma unroll
            for (int r = 0; r < 4; ++r)
                dpart[slot * 64 + w * 16 + lq * 4 + r] = den[r];
        }
    }
}

// ---------------------------------------------------------------------------
// fixup: merge the two parity halves of each split (bh, qb>=16) tile.
// 512 blocks x 256 threads; 16 elements/thread.
// ---------------------------------------------------------------------------
__global__ __launch_bounds__(256) void fixup(
    const float* __restrict__ Opart, const float* __restrict__ dpart,
    bf16* __restrict__ AO)
{
    const int pi = blockIdx.x;             // (qb-16)*32 + bh
    const int qb = 16 + (pi >> 5);
    const int bh = pi & 31;
    const int b = bh >> 4, h = bh & 15;
    const int t = threadIdx.x;
    const int row = t >> 2;                // 0..63
    const int c0 = (t & 3) * 16;
    const float dA = dpart[(pi * 2) * 64 + row];
    const float dB = dpart[(pi * 2 + 1) * 64 + row];
    const float inv = 1.0f / (dA + dB);
    const float* A = Opart + (size_t)(pi * 2) * 4096 + row * 64 + c0;
    const float* B = Opart + (size_t)(pi * 2 + 1) * 4096 + row * 64 + c0;
    bf16* dst = AO + ((size_t)b * 2048 + qb * 64 + row) * 1024 + h * 64 + c0;
#pragma unroll
    for (int c = 0; c < 16; c += 4) {
        bf16 tt[4];
#pragma unroll
        for (int r = 0; r < 4; ++r)
            tt[r] = __float2bfloat16((A[c + r] + B[c + r]) * inv);
        *(uint2*)&dst[c] = *(uint2*)tt;
    }
}

// ---------------------------------------------------------------------------
extern "C" void kernel_launch(void* const* d_in, const int* in_sizes, int n_in,
                              void* d_out, int out_size, void* d_ws, size_t ws_size,
                              hipStream_t stream)
{
    const float* x  = (const float*)d_in[0];
    const float* Wq = (const float*)d_in[1];
    const float* bq = (const float*)d_in[2];
    const float* Wk = (const float*)d_in[3];
    const float* bk = (const float*)d_in[4];
    const float* Wv = (const float*)d_in[5];
    const float* bv = (const float*)d_in[6];
    const float* Er = (const float*)d_in[7];
    const float* Wo = (const float*)d_in[8];
    const float* bo = (const float*)d_in[9];
    float* out = (float*)d_out;

    bf16* ws = (bf16*)d_ws;
    const size_t NEl = (size_t)4096 * 1024;
    bf16* Qw  = ws;                 // (b,h,s,d); K follows contiguously
    bf16* Kw  = ws + NEl;
    bf16* Vtw = ws + 3 * NEl;       // (b,h,d,s) — written directly by gemm z==2
    bf16* xb  = ws + 4 * NEl;       // bf16 x; dead after QKV gemm
    bf16* AOw = xb;                 // aliased
    bf16* Wqb = ws + 5 * NEl;       // Wq|Wk|Wv contiguous -> one N=3072 GEMM
    bf16* Wkb = Wqb + 1024 * 1024;
    bf16* Wvb = Wkb + 1024 * 1024;
    bf16* Wob = Wvb + 1024 * 1024;
    bf16* Erb = Wob + 1024 * 1024;
    float* dpart = (float*)(Erb + (size_t)2048 * 64);   // 1024*64 fp32 = 256 KB
    // fp32 O-partials in d_out (dead until final GEMM): 1024 slots * 16 KB
    float* Opart = out;
    (void)Kw;

    cast_all<<<dim3(4096, 6), 256, 0, stream>>>(x, Wq, Wk, Wv, Wo, Er,
                                                xb, Wqb, Wkb, Wvb, Wob, Erb);
    // fused QKV: N=3072 over contiguous Wq|Wk|Wv; Q,K headmajor; V -> Vt direct
    gemm_nt<<<dim3(24, 32), 256, 0, stream>>>(xb, Wqb, bq, bk, bv, Qw, Vtw, nullptr);
    attn<<<dim3(1536), 256, 0, stream>>>(Qw, Kw, Vtw, Erb, AOw, Opart, dpart);
    fixup<<<dim3(512), 256, 0, stream>>>(Opart, dpart, AOw);
    // output projection: N=1024, fp32 rowmajor into d_out
    gemm_nt<<<dim3(8, 32), 256, 0, stream>>>(AOw, Wob, bo, bo, bo, nullptr, nullptr, out);
}

// Round 15
// 269.805 us; speedup vs baseline: 1.0308x; 1.0308x over previous
//
#include <hip/hip_runtime.h>
#include <hip/hip_bf16.h>

typedef short v8s __attribute__((ext_vector_type(8)));
typedef float v4f __attribute__((ext_vector_type(4)));
typedef __hip_bfloat16 bf16;
typedef unsigned int u32;

#define MFMA(a, b, c) __builtin_amdgcn_mfma_f32_16x16x32_bf16(a, b, c, 0, 0, 0)

// direct global->LDS DMA, 16B per lane. LDS dest = wave-uniform base + lane*16.
__device__ __forceinline__ void gload16(const bf16* g, bf16* l) {
    __builtin_amdgcn_global_load_lds(
        (const __attribute__((address_space(1))) u32*)(g),
        (__attribute__((address_space(3))) u32*)(l), 16, 0, 0);
}

// ---------------------------------------------------------------------------
// All fp32->bf16 casts in ONE launch. grid=(4096,6); region r sized n4 vec4s.
// ---------------------------------------------------------------------------
__global__ __launch_bounds__(256) void cast_all(
    const float* __restrict__ x,  const float* __restrict__ wq,
    const float* __restrict__ wk, const float* __restrict__ wv,
    const float* __restrict__ wo, const float* __restrict__ er,
    bf16* __restrict__ xb,  bf16* __restrict__ wqb, bf16* __restrict__ wkb,
    bf16* __restrict__ wvb, bf16* __restrict__ wob, bf16* __restrict__ erb)
{
    const int r = blockIdx.y;
    const float* s; bf16* d; int n4;
    if      (r == 0) { s = x;  d = xb;  n4 = 1048576; }
    else if (r == 1) { s = wq; d = wqb; n4 = 262144;  }
    else if (r == 2) { s = wk; d = wkb; n4 = 262144;  }
    else if (r == 3) { s = wv; d = wvb; n4 = 262144;  }
    else if (r == 4) { s = wo; d = wob; n4 = 262144;  }
    else             { s = er; d = erb; n4 = 32768;   }
    const int i = blockIdx.x * 256 + threadIdx.x;
    if (i < n4) {
        const float4 v = ((const float4*)s)[i];
        bf16 t[4];
        t[0] = __float2bfloat16(v.x);
        t[1] = __float2bfloat16(v.y);
        t[2] = __float2bfloat16(v.z);
        t[3] = __float2bfloat16(v.w);
        ((uint2*)d)[i] = *(const uint2*)t;
    }
}

// ---------------------------------------------------------------------------
// NT GEMM v4 (final; R6 probe: qkv+proj ~65 us total ~530 TF, on the
// m97-structure shape curve for K=1024 — structural limit for this template).
// ---------------------------------------------------------------------------
__global__ __launch_bounds__(256) void gemm_nt(
    const bf16* __restrict__ A, const bf16* __restrict__ W,
    const float* __restrict__ b0, const float* __restrict__ b1,
    const float* __restrict__ b2,
    bf16* __restrict__ oHM, bf16* __restrict__ Vt, float* __restrict__ outf)
{
    __shared__ bf16 As[2][128 * 64];
    __shared__ bf16 Bs[2][128 * 64];

    const int tid = threadIdx.x;
    const int w  = tid >> 6, l = tid & 63;
    const int lm = l & 15,  lq = l >> 4;
    const int wm = (w >> 1) * 64, wn = (w & 1) * 64;
    const int m0 = blockIdx.y * 128, n0 = blockIdx.x * 128;

    const int grow = l >> 3;                       // 0..7, == row&7
    const int gcol = ((l & 7) ^ grow) * 8;         // bf16 units, 16B granules

    v4f acc[4][4];
#pragma unroll
    for (int i = 0; i < 4; ++i)
#pragma unroll
        for (int j = 0; j < 4; ++j) acc[i][j] = (v4f){0.f, 0.f, 0.f, 0.f};

    const int sw = (lm & 7) << 4;

    auto STAGE = [&](int p, int k0) {
#pragma unroll
        for (int q = 0; q < 4; ++q) {
            const int rr = w * 32 + q * 8;
            gload16(&A[(size_t)(m0 + rr + grow) * 1024 + k0 + gcol], &As[p][rr * 64]);
            gload16(&W[(size_t)(n0 + rr + grow) * 1024 + k0 + gcol], &Bs[p][rr * 64]);
        }
    };
    auto COMPUTE = [&](int p) {
#pragma unroll
        for (int kk = 0; kk < 2; ++kk) {
            v8s a[4], b[4];
            const int cb = (lq * 16 + kk * 64);
#pragma unroll
            for (int i = 0; i < 4; ++i) {
                const int row = wm + i * 16 + lm;
                a[i] = *(const v8s*)((const char*)As[p] + row * 128 + (cb ^ sw));
            }
#pragma unroll
            for (int j = 0; j < 4; ++j) {
                const int row = wn + j * 16 + lm;
                b[j] = *(const v8s*)((const char*)Bs[p] + row * 128 + (cb ^ sw));
            }
#pragma unroll
            for (int i = 0; i < 4; ++i)
#pragma unroll
                for (int j = 0; j < 4; ++j)
                    acc[i][j] = MFMA(b[j], a[i], acc[i][j]);   // SWAPPED: C^T frag
        }
    };

    STAGE(0, 0);
    __syncthreads();                               // tile 0 landed
    for (int t = 0; t < 15; ++t) {
        STAGE((t + 1) & 1, (t + 1) * 64);          // issue next tile's DMA
        COMPUTE(t & 1);                            // overlap under it
        __syncthreads();                           // drain vmcnt; all reads done
    }
    COMPUTE(1);                                    // tile 15

    const int z = blockIdx.x >> 3;                 // 1024-col slab
    const float* bias = (z == 0) ? b0 : (z == 1) ? b1 : b2;

    float4 bj[4];
#pragma unroll
    for (int j = 0; j < 4; ++j)
        bj[j] = *(const float4*)&bias[(n0 & 1023) + wn + j * 16 + lq * 4];

#pragma unroll
    for (int i = 0; i < 4; ++i) {
        const int row = m0 + wm + i * 16 + lm;     // one row per lane
        const int bb = row >> 11, ss = row & 2047;
#pragma unroll
        for (int j = 0; j < 4; ++j) {
            const int cc = (n0 & 1023) + wn + j * 16 + lq * 4;
            const float v0 = acc[i][j][0] + bj[j].x;
            const float v1 = acc[i][j][1] + bj[j].y;
            const float v2 = acc[i][j][2] + bj[j].z;
            const float v3 = acc[i][j][3] + bj[j].w;
            if (outf) {
                const float4 fv = {v0, v1, v2, v3};
                *(float4*)&outf[(size_t)row * 1024 + cc] = fv;
            } else {
                bf16 t[4];
                t[0] = __float2bfloat16(v0);
                t[1] = __float2bfloat16(v1);
                t[2] = __float2bfloat16(v2);
                t[3] = __float2bfloat16(v3);
                const int hh = cc >> 6, dd = cc & 63;
                if (z < 2) {
                    *(uint2*)&oHM[(size_t)z * 4194304 +
                        ((size_t)(bb * 16 + hh) * 2048 + ss) * 64 + dd] = *(uint2*)t;
                } else {
#pragma unroll
                    for (int r = 0; r < 4; ++r)
                        Vt[((size_t)(bb * 16 + hh) * 64 + dd + r) * 2048 + ss] = t[r];
                }
            }
        }
    }
}

// ---------------------------------------------------------------------------
// Segment schedule tables (48 segments per bh, longest-first).
// TT: 0 = even-parity half, 1 = odd-parity half, 2 = full block.
// ---------------------------------------------------------------------------
__device__ const unsigned char QBt[48] = {
    31,31,30,15, 30,29,29,28,14, 28,27,27,26,13, 26,25,25,24,12,
    24,23,23,22,11, 22,21,21,20,10, 20,19,19,18,9, 18,17,17,16,8,
    16,7, 6,5,4,3,2,1,0};
__device__ const unsigned char TTt[48] = {
     0, 1, 0, 2,  1, 0, 1, 0, 2,  1, 0, 1, 0, 2,  1, 0, 1, 0, 2,
     1, 0, 1, 0, 2,  1, 0, 1, 0, 2,  1, 0, 1, 0, 2,  1, 0, 1, 0, 2,
     1, 2, 2,2,2,2,2,2,2};

// ---------------------------------------------------------------------------
// Flash attention + skewed rel-pos bias — FINAL (R13 build, session best:
// 115.7 us attn, 271.06 us total; start was 280.4).
// Structure: S^T scores (MFMA(k,q)/(e,q): lane holds q-row lm, vectorized
// lane-uniform G gather + P write); Ps overlaid into Gs2 (R12); K/V LDS
// double-buffered, register prefetch distance 2, ONE barrier/iter (R13,
// -5.4 us); tile-parity split-K for qb>=16 (R7: FETCH 63.6->14 MB, no
// atomics); max-free softmax P=exp(s-4), single epilogue reduce.
// Measured non-levers (all isolated on HW): occupancy 14-53% (null),
// bank conflicts 7.0->1.6M (null), DS-op count -40% (null), split-K
// balance (null/neg), K/V staging removal (-100 us — staging IS the
// latency amortizer), T5 setprio (-7.8 us: deprioritizes prefetch issue).
// Residual: in-wave dependency-chain latency (MfmaUtil 10%, VALUBusy 27%,
// no pipe >28%) — structural floor for this tile size in plain HIP.
// ---------------------------------------------------------------------------
__global__ __launch_bounds__(256, 3) void attn(
    const bf16* __restrict__ Q, const bf16* __restrict__ K,
    const bf16* __restrict__ Vt, const bf16* __restrict__ Er,
    bf16* __restrict__ AO, float* __restrict__ Opart, float* __restrict__ dpart)
{
    __shared__ bf16 Ks[2][64 * 72];
    __shared__ bf16 Vs[2][64 * 72];
    __shared__ bf16 Gs2[64 * 104];  // G band (shifted cols 1..95) + P (cols 0..63)

    const int ord = blockIdx.x;
    const int bh = ord & 31;
    const int s  = ord >> 5;
    const int qb = QBt[s];
    const int tt = TTt[s];
    const int t0   = (tt == 2) ? 0 : tt;           // first tile
    const int step = (tt == 2) ? 1 : 2;            // tile stride
    const int slot = (tt == 2) ? -1 : (((qb - 16) * 32 + bh) * 2 + tt);
    const int N    = (qb - t0) / step + 1;         // iterations

    const int i0 = qb * 64;
    const int b  = bh >> 4, h = bh & 15;
    const int tid = threadIdx.x;
    const int w  = tid >> 6, l = tid & 63;
    const int lm = l & 15,  lq = l >> 4;

    const bf16* qp = Q + ((size_t)bh * 2048 + i0 + w * 16 + lm) * 64 + lq * 8;
    const v8s q0 = *(const v8s*)qp;
    const v8s q1f = *(const v8s*)(qp + 32);

    v4f accO[4];
#pragma unroll
    for (int dt = 0; dt < 4; ++dt) accO[dt] = (v4f){0.f, 0.f, 0.f, 0.f};
    float rsc = 0.f;                   // denominator for q-row i = lm (this lane)

    const int sr0 = tid >> 3;          // 0..31 (+32 on rep1)
    const int sc8 = (tid & 7) * 8;
    const size_t kbase = (size_t)bh * 2048 * 64;
    const size_t vbase = (size_t)bh * 64 * 2048;

    const int grow_g = (w * 16 + lm) * 104;        // this lane's G/P row base
    const int ig     = i0 + w * 16 + lm;           // global q row

    // prologue: stage tile t0 into buf0; prefetch regs <- tile t0+step
    {
        const int jt0 = t0 * 64;
        const uint4 a0 = *(const uint4*)&K[kbase + (size_t)(jt0 + sr0) * 64 + sc8];
        const uint4 a1 = *(const uint4*)&K[kbase + (size_t)(jt0 + sr0 + 32) * 64 + sc8];
        const uint4 c0 = *(const uint4*)&Vt[vbase + (size_t)sr0 * 2048 + jt0 + sc8];
        const uint4 c1 = *(const uint4*)&Vt[vbase + (size_t)(sr0 + 32) * 2048 + jt0 + sc8];
        *(uint4*)&Ks[0][sr0 * 72 + sc8]        = a0;
        *(uint4*)&Ks[0][(sr0 + 32) * 72 + sc8] = a1;
        *(uint4*)&Vs[0][sr0 * 72 + sc8]        = c0;
        *(uint4*)&Vs[0][(sr0 + 32) * 72 + sc8] = c1;
    }
    uint4 kp0, kp1, vp0, vp1;
    if (N > 1) {
        const int jn = (t0 + step) * 64;
        kp0 = *(const uint4*)&K[kbase + (size_t)(jn + sr0) * 64 + sc8];
        kp1 = *(const uint4*)&K[kbase + (size_t)(jn + sr0 + 32) * 64 + sc8];
        vp0 = *(const uint4*)&Vt[vbase + (size_t)sr0 * 2048 + jn + sc8];
        vp1 = *(const uint4*)&Vt[vbase + (size_t)(sr0 + 32) * 2048 + jn + sc8];
    }

    for (int n = 0; n < N; ++n) {
        const int it = t0 + n * step;
        const int j0 = it * 64;
        const int p  = n & 1;
        __syncthreads();   // buf p (staged last iter / prologue) visible;
                           // buf p^1 reads from iter n-1 complete (WAR)
        if (n + 1 < N) {   // stage next tile into buf p^1 from prefetch regs
            bf16* kd = Ks[p ^ 1];
            bf16* vd = Vs[p ^ 1];
            *(uint4*)&kd[sr0 * 72 + sc8]        = kp0;
            *(uint4*)&kd[(sr0 + 32) * 72 + sc8] = kp1;
            *(uint4*)&vd[sr0 * 72 + sc8]        = vp0;
            *(uint4*)&vd[(sr0 + 32) * 72 + sc8] = vp1;
            if (n + 2 < N) {                  // prefetch tile n+2 (distance 2)
                const int jn = (it + 2 * step) * 64;
                kp0 = *(const uint4*)&K[kbase + (size_t)(jn + sr0) * 64 + sc8];
                kp1 = *(const uint4*)&K[kbase + (size_t)(jn + sr0 + 32) * 64 + sc8];
                vp0 = *(const uint4*)&Vt[vbase + (size_t)sr0 * 2048 + jn + sc8];
                vp1 = *(const uint4*)&Vt[vbase + (size_t)(sr0 + 32) * 2048 + jn + sc8];
            }
        }
        // G band, S^T: MFMA(e,q) -> lane holds q-row lm, col'=ct2*16+lq*4+r;
        // store row-shifted by lm+1 (cols 1..95).
        const int basew = 2048 - 16 - i0 + j0 - 16 * w;
#pragma unroll
        for (int ct2 = 0; ct2 < 5; ++ct2) {
            int mr = basew + ct2 * 16 + lm;
            mr = (mr > 2047) ? 2047 : mr;      // clamped rows feed masked cols only
            const bf16* ep = Er + (size_t)mr * 64 + lq * 8;
            const v8s e0 = *(const v8s*)ep;
            const v8s e1 = *(const v8s*)(ep + 32);
            v4f g = (v4f){0.f, 0.f, 0.f, 0.f};
            g = MFMA(e0, q0, g);
            g = MFMA(e1, q1f, g);
            const int cb = ct2 * 16 + lq * 4 + lm + 1;
#pragma unroll
            for (int r = 0; r < 4; ++r)
                Gs2[grow_g + cb + r] = __float2bfloat16(g[r] * 0.125f);
        }
        // G-store -> G-read: lane-private row; HW DS in-order per wave;
        // compiler fence blocks strict-aliasing reordering (v10's failure mode)
        asm volatile("" ::: "memory");
        // QK^T, S^T from buf p
        v4f sv[4];
#pragma unroll
        for (int ct = 0; ct < 4; ++ct) {
            const v8s k0f = *(const v8s*)&Ks[p][(ct * 16 + lm) * 72 + lq * 8];
            const v8s k1f = *(const v8s*)&Ks[p][(ct * 16 + lm) * 72 + 32 + lq * 8];
            v4f s2 = (v4f){0.f, 0.f, 0.f, 0.f};
            s2 = MFMA(k0f, q0, s2);
            s2 = MFMA(k1f, q1f, s2);
            sv[ct] = s2;
        }
        // scores: G gather (col 16+jj), mask+exp, P^T write into cols jj
        // (overlay: write at ct kills only the G read by this lane at ct-1)
#pragma unroll
        for (int ct = 0; ct < 4; ++ct) {
            const uint2 graw = *(const uint2*)&Gs2[grow_g + 16 + ct * 16 + lq * 4];
            const bf16* gb4 = (const bf16*)&graw;
            bf16 pt[4];
#pragma unroll
            for (int r = 0; r < 4; ++r) {
                const int jj = ct * 16 + lq * 4 + r;
                float sc = fmaf(sv[ct][r], 0.125f, (float)gb4[r]);
                if (j0 + jj > ig) sc = -1e9f;
                const float pe = __expf(sc - 4.0f);
                rsc += pe;
                pt[r] = __float2bfloat16(pe);
            }
            *(uint2*)&Gs2[grow_g + ct * 16 + lq * 4] = *(const uint2*)pt;
        }
        // PV: P from Gs2 cols 0..63 (proven unguarded same-wave pattern),
        // V from buf p
        const v8s pa0 = *(const v8s*)&Gs2[grow_g + lq * 8];
        const v8s pa1 = *(const v8s*)&Gs2[grow_g + 32 + lq * 8];
#pragma unroll
        for (int dt = 0; dt < 4; ++dt) {
            const v8s vb0 = *(const v8s*)&Vs[p][(dt * 16 + lm) * 72 + lq * 8];
            const v8s vb1 = *(const v8s*)&Vs[p][(dt * 16 + lm) * 72 + 32 + lq * 8];
            accO[dt] = MFMA(pa0, vb0, accO[dt]);
            accO[dt] = MFMA(pa1, vb1, accO[dt]);
        }
    }
    // denominator: sum the 4 lq replicas of row lm, broadcast to acc rows
    rsc += __shfl_xor(rsc, 16, 64);
    rsc += __shfl_xor(rsc, 32, 64);
    float den[4];
#pragma unroll
    for (int r = 0; r < 4; ++r) den[r] = __shfl(rsc, lq * 4 + r, 64);

    if (slot < 0) {
        // sole owner: normalize and store bf16
#pragma unroll
        for (int dt = 0; dt < 4; ++dt) {
#pragma unroll
            for (int r = 0; r < 4; ++r) {
                const int row = i0 + w * 16 + lq * 4 + r;
                const int d   = dt * 16 + lm;
                AO[((size_t)b * 2048 + row) * 1024 + h * 64 + d] =
                    __float2bfloat16(accO[dt][r] / den[r]);
            }
        }
    } else {
        // parity half: fp32 partials to a private slot (no atomics)
        float* op = Opart + (size_t)slot * 4096;
#pragma unroll
        for (int dt = 0; dt < 4; ++dt) {
#pragma unroll
            for (int r = 0; r < 4; ++r) {
                const int row = w * 16 + lq * 4 + r;
                op[row * 64 + dt * 16 + lm] = accO[dt][r];
            }
        }
        if (lm == 0) {
#pragma unroll
            for (int r = 0; r < 4; ++r)
                dpart[slot * 64 + w * 16 + lq * 4 + r] = den[r];
        }
    }
}

// ---------------------------------------------------------------------------
// fixup: merge the two parity halves of each split (bh, qb>=16) tile.
// 512 blocks x 256 threads; 16 elements/thread.
// ---------------------------------------------------------------------------
__global__ __launch_bounds__(256) void fixup(
    const float* __restrict__ Opart, const float* __restrict__ dpart,
    bf16* __restrict__ AO)
{
    const int pi = blockIdx.x;             // (qb-16)*32 + bh
    const int qb = 16 + (pi >> 5);
    const int bh = pi & 31;
    const int b = bh >> 4, h = bh & 15;
    const int t = threadIdx.x;
    const int row = t >> 2;                // 0..63
    const int c0 = (t & 3) * 16;
    const float dA = dpart[(pi * 2) * 64 + row];
    const float dB = dpart[(pi * 2 + 1) * 64 + row];
    const float inv = 1.0f / (dA + dB);
    const float* A = Opart + (size_t)(pi * 2) * 4096 + row * 64 + c0;
    const float* B = Opart + (size_t)(pi * 2 + 1) * 4096 + row * 64 + c0;
    bf16* dst = AO + ((size_t)b * 2048 + qb * 64 + row) * 1024 + h * 64 + c0;
#pragma unroll
    for (int c = 0; c < 16; c += 4) {
        bf16 tt[4];
#pragma unroll
        for (int r = 0; r < 4; ++r)
            tt[r] = __float2bfloat16((A[c + r] + B[c + r]) * inv);
        *(uint2*)&dst[c] = *(uint2*)tt;
    }
}

// ---------------------------------------------------------------------------
extern "C" void kernel_launch(void* const* d_in, const int* in_sizes, int n_in,
                              void* d_out, int out_size, void* d_ws, size_t ws_size,
                              hipStream_t stream)
{
    const float* x  = (const float*)d_in[0];
    const float* Wq = (const float*)d_in[1];
    const float* bq = (const float*)d_in[2];
    const float* Wk = (const float*)d_in[3];
    const float* bk = (const float*)d_in[4];
    const float* Wv = (const float*)d_in[5];
    const float* bv = (const float*)d_in[6];
    const float* Er = (const float*)d_in[7];
    const float* Wo = (const float*)d_in[8];
    const float* bo = (const float*)d_in[9];
    float* out = (float*)d_out;

    bf16* ws = (bf16*)d_ws;
    const size_t NEl = (size_t)4096 * 1024;
    bf16* Qw  = ws;                 // (b,h,s,d); K follows contiguously
    bf16* Kw  = ws + NEl;
    bf16* Vtw = ws + 3 * NEl;       // (b,h,d,s) — written directly by gemm z==2
    bf16* xb  = ws + 4 * NEl;       // bf16 x; dead after QKV gemm
    bf16* AOw = xb;                 // aliased
    bf16* Wqb = ws + 5 * NEl;       // Wq|Wk|Wv contiguous -> one N=3072 GEMM
    bf16* Wkb = Wqb + 1024 * 1024;
    bf16* Wvb = Wkb + 1024 * 1024;
    bf16* Wob = Wvb + 1024 * 1024;
    bf16* Erb = Wob + 1024 * 1024;
    float* dpart = (float*)(Erb + (size_t)2048 * 64);   // 1024*64 fp32 = 256 KB
    // fp32 O-partials in d_out (dead until final GEMM): 1024 slots * 16 KB
    float* Opart = out;
    (void)Kw;

    cast_all<<<dim3(4096, 6), 256, 0, stream>>>(x, Wq, Wk, Wv, Wo, Er,
                                                xb, Wqb, Wkb, Wvb, Wob, Erb);
    // fused QKV: N=3072 over contiguous Wq|Wk|Wv; Q,K headmajor; V -> Vt direct
    gemm_nt<<<dim3(24, 32), 256, 0, stream>>>(xb, Wqb, bq, bk, bv, Qw, Vtw, nullptr);
    attn<<<dim3(1536), 256, 0, stream>>>(Qw, Kw, Vtw, Erb, AOw, Opart, dpart);
    fixup<<<dim3(512), 256, 0, stream>>>(Opart, dpart, AOw);
    // output projection: N=1024, fp32 rowmajor into d_out
    gemm_nt<<<dim3(8, 32), 256, 0, stream>>>(AOw, Wob, bo, bo, bo, nullptr, nullptr, out);
}